// Round 3
// baseline (6190.431 us; speedup 1.0000x reference)
//
#include <hip/hip_runtime.h>

#define N_NODES 50000
#define N_EDGES 800000
#define HEADS 8
#define HD 16
#define F 128
#define RPB 16   // rows per block in projection kernel

// ---- monotone float<->uint encoding for atomicMax on floats ----
__device__ __forceinline__ unsigned enc_f(float x) {
    unsigned b = __float_as_uint(x);
    return (b & 0x80000000u) ? ~b : (b | 0x80000000u);
}
__device__ __forceinline__ float dec_f(unsigned u) {
    return (u & 0x80000000u) ? __uint_as_float(u ^ 0x80000000u)
                             : __uint_as_float(~u);
}

// mish(x) = x * tanh(softplus(x)) = x * (z^2-1)/(z^2+1), z = 1+e^x
__device__ __forceinline__ float mish_f(float x) {
    if (x > 20.0f) return x;           // tanh(softplus) == 1.0f in fp32
    float z = 1.0f + expf(x);
    float z2 = z * z;
    return x * (z2 - 1.0f) / (z2 + 1.0f);
}

// ---- K1: dual projection GEMM: Ps = nodes@Ws + bs ; Pr = nodes@Wr + br ----
__global__ __launch_bounds__(128) void k_proj(
        const float* __restrict__ nodes,
        const float* __restrict__ Ws, const float* __restrict__ Wsb,
        const float* __restrict__ Wr, const float* __restrict__ Wrb,
        float* __restrict__ Ps, float* __restrict__ Pr) {
    __shared__ float rows[RPB][F];
    const int o  = threadIdx.x;          // output column 0..127
    const int r0 = blockIdx.x * RPB;
    for (int i = 0; i < RPB; ++i)
        rows[i][o] = nodes[(r0 + i) * F + o];
    __syncthreads();

    float accs[RPB], accr[RPB];
    const float bs = Wsb[o], br = Wrb[o];
    #pragma unroll
    for (int i = 0; i < RPB; ++i) { accs[i] = bs; accr[i] = br; }

    for (int f = 0; f < F; ++f) {
        const float ws = Ws[f * F + o];
        const float wr = Wr[f * F + o];
        #pragma unroll
        for (int i = 0; i < RPB; ++i) {
            accs[i] = fmaf(rows[i][f], ws, accs[i]);
            accr[i] = fmaf(rows[i][f], wr, accr[i]);
        }
    }
    #pragma unroll
    for (int i = 0; i < RPB; ++i) {
        Ps[(r0 + i) * F + o] = accs[i];
        Pr[(r0 + i) * F + o] = accr[i];
    }
}

// ---- K2: per (edge,head): logit = dot(mish(Ps[s]+Pr[r]), attn_k) + b;
//          segment max via encoded atomicMax ----
__global__ __launch_bounds__(256) void k_edge_logits(
        const int* __restrict__ senders, const int* __restrict__ receivers,
        const float* __restrict__ Ps, const float* __restrict__ Pr,
        const float* __restrict__ attn_k, const float* __restrict__ attn_b,
        float* __restrict__ logits, unsigned* __restrict__ segmax) {
    const int tid = blockIdx.x * blockDim.x + threadIdx.x;
    if (tid >= N_EDGES * HEADS) return;
    const int e = tid >> 3, h = tid & 7;
    const int s = senders[e], r = receivers[e];
    const float4* ps = (const float4*)(Ps + s * F + h * HD);
    const float4* pr = (const float4*)(Pr + r * F + h * HD);
    const float4* ak = (const float4*)attn_k;
    float logit = attn_b[0];
    #pragma unroll
    for (int q = 0; q < 4; ++q) {
        float4 a = ps[q], b = pr[q], k = ak[q];
        logit += mish_f(a.x + b.x) * k.x + mish_f(a.y + b.y) * k.y
               + mish_f(a.z + b.z) * k.z + mish_f(a.w + b.w) * k.w;
    }
    logits[tid] = logit;
    atomicMax(segmax + r * HEADS + h, enc_f(logit));
}

// ---- K3: denom[r,h] += exp(logit - segmax) ----
__global__ __launch_bounds__(256) void k_denom(
        const int* __restrict__ receivers,
        const float* __restrict__ logits,
        const unsigned* __restrict__ segmax,
        float* __restrict__ denom) {
    const int tid = blockIdx.x * blockDim.x + threadIdx.x;
    if (tid >= N_EDGES * HEADS) return;
    const int e = tid >> 3, h = tid & 7;
    const int ih = receivers[e] * HEADS + h;
    const float w = expf(logits[tid] - dec_f(segmax[ih]));
    atomicAdd(denom + ih, w);
}

// ---- K4: out[r, h*16+d] += Ps[s, h*16+d] * weight ----
__global__ __launch_bounds__(256) void k_agg(
        const int* __restrict__ senders, const int* __restrict__ receivers,
        const float* __restrict__ logits,
        const unsigned* __restrict__ segmax, const float* __restrict__ denom,
        const float* __restrict__ Ps, float* __restrict__ out) {
    const int tid = blockIdx.x * blockDim.x + threadIdx.x;
    if (tid >= N_EDGES * HEADS) return;
    const int e = tid >> 3, h = tid & 7;
    const int s = senders[e], r = receivers[e];
    const int ih = r * HEADS + h;
    const float wgt = expf(logits[tid] - dec_f(segmax[ih])) / denom[ih];
    const float4* ps = (const float4*)(Ps + s * F + h * HD);
    float* o = out + r * F + h * HD;
    #pragma unroll
    for (int q = 0; q < 4; ++q) {
        float4 a = ps[q];
        atomicAdd(o + q * 4 + 0, a.x * wgt);
        atomicAdd(o + q * 4 + 1, a.y * wgt);
        atomicAdd(o + q * 4 + 2, a.z * wgt);
        atomicAdd(o + q * 4 + 3, a.w * wgt);
    }
}

extern "C" void kernel_launch(void* const* d_in, const int* in_sizes, int n_in,
                              void* d_out, int out_size, void* d_ws, size_t ws_size,
                              hipStream_t stream) {
    const float* nodes     = (const float*)d_in[0];
    const int*   senders   = (const int*)  d_in[1];
    const int*   receivers = (const int*)  d_in[2];
    const float* Wsk       = (const float*)d_in[3];
    const float* Wsb       = (const float*)d_in[4];
    const float* Wrk       = (const float*)d_in[5];
    const float* Wrb       = (const float*)d_in[6];
    const float* attnk     = (const float*)d_in[7];
    const float* attnb     = (const float*)d_in[8];
    float* out = (float*)d_out;

    // workspace layout
    float*    Ps     = (float*)d_ws;                       // N*F
    float*    Pr     = Ps + (size_t)N_NODES * F;           // N*F
    float*    logits = Pr + (size_t)N_NODES * F;           // E*H
    unsigned* segmax = (unsigned*)(logits + (size_t)N_EDGES * HEADS); // N*H
    float*    denom  = (float*)(segmax + (size_t)N_NODES * HEADS);    // N*H

    hipMemsetAsync(segmax, 0, (size_t)N_NODES * HEADS * sizeof(unsigned), stream);
    hipMemsetAsync(denom,  0, (size_t)N_NODES * HEADS * sizeof(float), stream);
    hipMemsetAsync(out,    0, (size_t)N_NODES * F * sizeof(float), stream);

    k_proj<<<N_NODES / RPB, 128, 0, stream>>>(nodes, Wsk, Wsb, Wrk, Wrb, Ps, Pr);

    const int total  = N_EDGES * HEADS;
    const int blocks = (total + 255) / 256;
    k_edge_logits<<<blocks, 256, 0, stream>>>(senders, receivers, Ps, Pr,
                                              attnk, attnb, logits, segmax);
    k_denom<<<blocks, 256, 0, stream>>>(receivers, logits, segmax, denom);
    k_agg<<<blocks, 256, 0, stream>>>(senders, receivers, logits, segmax, denom,
                                      Ps, out);
}

// Round 4
// 692.247 us; speedup vs baseline: 8.9425x; 8.9425x over previous
//
#include <hip/hip_runtime.h>

#define N_NODES 50000
#define N_EDGES 800000
#define HEADS 8
#define HD 16
#define F 128
#define RPB 16   // rows per block in projection kernel

// mish(x) = x * tanh(softplus(x)) = x * (z^2-1)/(z^2+1), z = 1+e^x
__device__ __forceinline__ float mish_f(float x) {
    if (x > 20.0f) return x;           // tanh(softplus) == 1.0f in fp32
    float z = 1.0f + expf(x);
    float z2 = z * z;
    return x * (z2 - 1.0f) / (z2 + 1.0f);
}

// ---- K1: dual projection GEMM: Ps = nodes@Ws + bs ; Pr = nodes@Wr + br ----
__global__ __launch_bounds__(128) void k_proj(
        const float* __restrict__ nodes,
        const float* __restrict__ Ws, const float* __restrict__ Wsb,
        const float* __restrict__ Wr, const float* __restrict__ Wrb,
        float* __restrict__ Ps, float* __restrict__ Pr) {
    __shared__ float rows[RPB][F];
    const int o  = threadIdx.x;          // output column 0..127
    const int r0 = blockIdx.x * RPB;
    for (int i = 0; i < RPB; ++i)
        rows[i][o] = nodes[(r0 + i) * F + o];
    __syncthreads();

    float accs[RPB], accr[RPB];
    const float bs = Wsb[o], br = Wrb[o];
    #pragma unroll
    for (int i = 0; i < RPB; ++i) { accs[i] = bs; accr[i] = br; }

    for (int f = 0; f < F; ++f) {
        const float ws = Ws[f * F + o];
        const float wr = Wr[f * F + o];
        #pragma unroll
        for (int i = 0; i < RPB; ++i) {
            accs[i] = fmaf(rows[i][f], ws, accs[i]);
            accr[i] = fmaf(rows[i][f], wr, accr[i]);
        }
    }
    #pragma unroll
    for (int i = 0; i < RPB; ++i) {
        Ps[(r0 + i) * F + o] = accs[i];
        Pr[(r0 + i) * F + o] = accr[i];
    }
}

// ---- K2: per (edge,head): logit = dot(mish(Ps[s]+Pr[r]), attn_k) + b ----
__global__ __launch_bounds__(256) void k_edge_logits(
        const int* __restrict__ senders, const int* __restrict__ receivers,
        const float* __restrict__ Ps, const float* __restrict__ Pr,
        const float* __restrict__ attn_k, const float* __restrict__ attn_b,
        float* __restrict__ logits) {
    const int tid = blockIdx.x * blockDim.x + threadIdx.x;
    if (tid >= N_EDGES * HEADS) return;
    const int e = tid >> 3, h = tid & 7;
    const int s = senders[e], r = receivers[e];
    const float4* ps = (const float4*)(Ps + s * F + h * HD);
    const float4* pr = (const float4*)(Pr + r * F + h * HD);
    const float4* ak = (const float4*)attn_k;
    float logit = attn_b[0];
    #pragma unroll
    for (int q = 0; q < 4; ++q) {
        float4 a = ps[q], b = pr[q], k = ak[q];
        logit += mish_f(a.x + b.x) * k.x + mish_f(a.y + b.y) * k.y
               + mish_f(a.z + b.z) * k.z + mish_f(a.w + b.w) * k.w;
    }
    logits[tid] = logit;
}

// ---- CSR build: histogram -> exclusive scan -> fill ----
__global__ __launch_bounds__(256) void k_hist(
        const int* __restrict__ receivers, int* __restrict__ counts) {
    const int e = blockIdx.x * blockDim.x + threadIdx.x;
    if (e < N_EDGES) atomicAdd(counts + receivers[e], 1);
}

__global__ __launch_bounds__(1024) void k_scan(
        const int* __restrict__ counts, int* __restrict__ starts) {
    __shared__ int buf[1024];
    __shared__ int s_carry;
    if (threadIdx.x == 0) s_carry = 0;
    __syncthreads();
    for (int base = 0; base < N_NODES; base += 1024) {
        const int i = base + (int)threadIdx.x;
        const int v = (i < N_NODES) ? counts[i] : 0;
        buf[threadIdx.x] = v;
        __syncthreads();
        for (int off = 1; off < 1024; off <<= 1) {
            const int t = (threadIdx.x >= (unsigned)off) ? buf[threadIdx.x - off] : 0;
            __syncthreads();
            buf[threadIdx.x] += t;
            __syncthreads();
        }
        const int carry = s_carry;
        if (i < N_NODES) starts[i] = carry + buf[threadIdx.x] - v;  // exclusive
        __syncthreads();
        if (threadIdx.x == 1023) s_carry = carry + buf[1023];
        __syncthreads();
    }
    if (threadIdx.x == 0) starts[N_NODES] = s_carry;
}

__global__ __launch_bounds__(256) void k_fill(
        const int* __restrict__ receivers, const int* __restrict__ starts,
        int* __restrict__ cursor, int* __restrict__ eidx) {
    const int e = blockIdx.x * blockDim.x + threadIdx.x;
    if (e >= N_EDGES) return;
    const int r = receivers[e];
    const int pos = atomicAdd(cursor + r, 1);
    eidx[starts[r] + pos] = e;
}

// ---- K4: one block per node; online softmax + register accumulation;
//          each output element written exactly once ----
__global__ __launch_bounds__(128) void k_agg_csr(
        const int* __restrict__ starts, const int* __restrict__ eidx,
        const int* __restrict__ senders, const float* __restrict__ logits,
        const float* __restrict__ Ps, float* __restrict__ out) {
    const int n = blockIdx.x;
    const int t = threadIdx.x;       // output element 0..127
    const int h = t >> 4;            // head
    const int e0 = starts[n], e1 = starts[n + 1];
    float m = -3.0e38f, d = 0.0f, acc = 0.0f;
    for (int i = e0; i < e1; ++i) {
        const int e = eidx[i];
        const int s = senders[e];
        const float lg = logits[e * HEADS + h];
        const float ps = Ps[s * F + t];
        if (lg > m) {                 // online softmax rescale
            const float r = __expf(m - lg);
            d *= r; acc *= r; m = lg;
        }
        const float w = __expf(lg - m);
        d += w;
        acc = fmaf(w, ps, acc);
    }
    out[n * F + t] = (d > 0.0f) ? acc / d : 0.0f;
}

extern "C" void kernel_launch(void* const* d_in, const int* in_sizes, int n_in,
                              void* d_out, int out_size, void* d_ws, size_t ws_size,
                              hipStream_t stream) {
    const float* nodes     = (const float*)d_in[0];
    const int*   senders   = (const int*)  d_in[1];
    const int*   receivers = (const int*)  d_in[2];
    const float* Wsk       = (const float*)d_in[3];
    const float* Wsb       = (const float*)d_in[4];
    const float* Wrk       = (const float*)d_in[5];
    const float* Wrb       = (const float*)d_in[6];
    const float* attnk     = (const float*)d_in[7];
    const float* attnb     = (const float*)d_in[8];
    float* out = (float*)d_out;

    // workspace layout (eidx aliases Pr, which is dead after k_edge_logits)
    float* Ps     = (float*)d_ws;                            // N*F
    float* Pr     = Ps + (size_t)N_NODES * F;                // N*F
    float* logits = Pr + (size_t)N_NODES * F;                // E*H
    int*   counts = (int*)(logits + (size_t)N_EDGES * HEADS);// N
    int*   starts = counts + N_NODES;                        // N+1
    int*   eidx   = (int*)Pr;                                // E (aliases Pr)

    hipMemsetAsync(counts, 0, N_NODES * sizeof(int), stream);

    k_proj<<<N_NODES / RPB, 128, 0, stream>>>(nodes, Wsk, Wsb, Wrk, Wrb, Ps, Pr);

    const int eh_blocks = (N_EDGES * HEADS + 255) / 256;
    k_edge_logits<<<eh_blocks, 256, 0, stream>>>(senders, receivers, Ps, Pr,
                                                 attnk, attnb, logits);

    const int e_blocks = (N_EDGES + 255) / 256;
    k_hist<<<e_blocks, 256, 0, stream>>>(receivers, counts);
    k_scan<<<1, 1024, 0, stream>>>(counts, starts);
    hipMemsetAsync(counts, 0, N_NODES * sizeof(int), stream);  // reuse as cursor
    k_fill<<<e_blocks, 256, 0, stream>>>(receivers, starts, counts, eidx);

    k_agg_csr<<<N_NODES, 128, 0, stream>>>(starts, eidx, senders, logits, Ps, out);
}

// Round 5
// 445.225 us; speedup vs baseline: 13.9040x; 1.5548x over previous
//
#include <hip/hip_runtime.h>

#define N_NODES 50000
#define N_EDGES 800000
#define HEADS 8
#define HD 16
#define F 128
#define RPB 16   // rows per block in projection kernel

// mish(x) = x * tanh(softplus(x)) = x * (z^2-1)/(z^2+1), z = 1+e^x
__device__ __forceinline__ float mish_f(float x) {
    if (x > 20.0f) return x;           // tanh(softplus) == 1.0f in fp32
    float z = 1.0f + expf(x);
    float z2 = z * z;
    return x * (z2 - 1.0f) / (z2 + 1.0f);
}

// ---- K1: dual projection GEMM: Ps = nodes@Ws + bs ; Pr = nodes@Wr + br ----
__global__ __launch_bounds__(128) void k_proj(
        const float* __restrict__ nodes,
        const float* __restrict__ Ws, const float* __restrict__ Wsb,
        const float* __restrict__ Wr, const float* __restrict__ Wrb,
        float* __restrict__ Ps, float* __restrict__ Pr) {
    __shared__ float rows[RPB][F];
    const int o  = threadIdx.x;          // output column 0..127
    const int r0 = blockIdx.x * RPB;
    for (int i = 0; i < RPB; ++i)
        rows[i][o] = nodes[(r0 + i) * F + o];
    __syncthreads();

    float accs[RPB], accr[RPB];
    const float bs = Wsb[o], br = Wrb[o];
    #pragma unroll
    for (int i = 0; i < RPB; ++i) { accs[i] = bs; accr[i] = br; }

    for (int f = 0; f < F; ++f) {
        const float ws = Ws[f * F + o];
        const float wr = Wr[f * F + o];
        #pragma unroll
        for (int i = 0; i < RPB; ++i) {
            accs[i] = fmaf(rows[i][f], ws, accs[i]);
            accr[i] = fmaf(rows[i][f], wr, accr[i]);
        }
    }
    #pragma unroll
    for (int i = 0; i < RPB; ++i) {
        Ps[(r0 + i) * F + o] = accs[i];
        Pr[(r0 + i) * F + o] = accr[i];
    }
}

// ---- CSR build: histogram -> exclusive scan -> fill (stores SENDER ids) ----
__global__ __launch_bounds__(256) void k_hist(
        const int* __restrict__ receivers, int* __restrict__ counts) {
    const int e = blockIdx.x * blockDim.x + threadIdx.x;
    if (e < N_EDGES) atomicAdd(counts + receivers[e], 1);
}

__global__ __launch_bounds__(1024) void k_scan(
        const int* __restrict__ counts, int* __restrict__ starts) {
    __shared__ int buf[1024];
    __shared__ int s_carry;
    if (threadIdx.x == 0) s_carry = 0;
    __syncthreads();
    for (int base = 0; base < N_NODES; base += 1024) {
        const int i = base + (int)threadIdx.x;
        const int v = (i < N_NODES) ? counts[i] : 0;
        buf[threadIdx.x] = v;
        __syncthreads();
        for (int off = 1; off < 1024; off <<= 1) {
            const int t = (threadIdx.x >= (unsigned)off) ? buf[threadIdx.x - off] : 0;
            __syncthreads();
            buf[threadIdx.x] += t;
            __syncthreads();
        }
        const int carry = s_carry;
        if (i < N_NODES) starts[i] = carry + buf[threadIdx.x] - v;  // exclusive
        __syncthreads();
        if (threadIdx.x == 1023) s_carry = carry + buf[1023];
        __syncthreads();
    }
    if (threadIdx.x == 0) starts[N_NODES] = s_carry;
}

__global__ __launch_bounds__(256) void k_fill(
        const int* __restrict__ senders, const int* __restrict__ receivers,
        const int* __restrict__ starts, int* __restrict__ cursor,
        int* __restrict__ slist) {
    const int e = blockIdx.x * blockDim.x + threadIdx.x;
    if (e >= N_EDGES) return;
    const int r = receivers[e];
    const int pos = atomicAdd(cursor + r, 1);
    slist[starts[r] + pos] = senders[e];
}

// ---- K4: fused logits + online softmax + aggregation.
//      One 128-thread block per node. Thread t owns output element t
//      (head h = t>>4, dim d = t&15). Per edge the coalesced Ps[s] row
//      read serves BOTH the logit dot-product and the accumulation. ----
__global__ __launch_bounds__(128) void k_agg_fused(
        const int* __restrict__ starts, const int* __restrict__ slist,
        const float* __restrict__ Ps, const float* __restrict__ Pr,
        const float* __restrict__ attn_k, const float* __restrict__ attn_b,
        float* __restrict__ out) {
    const int n = blockIdx.x;
    const int t = threadIdx.x;
    const int e0 = starts[n], e1 = starts[n + 1];
    const float pr = Pr[n * F + t];
    const float ak = attn_k[t & 15];
    const float bias = attn_b[0];

    float m = -3.0e38f, den = 0.0f, acc = 0.0f;
    int   s_nxt = 0;
    float ps_nxt = 0.0f;
    if (e0 < e1) { s_nxt = slist[e0]; ps_nxt = Ps[s_nxt * F + t]; }

    for (int i = e0; i < e1; ++i) {
        const float ps = ps_nxt;
        if (i + 1 < e1) {                      // prefetch next sender row
            s_nxt  = slist[i + 1];
            ps_nxt = Ps[s_nxt * F + t];
        }
        float x = mish_f(ps + pr) * ak;
        // butterfly sum across the 16-lane head group (all lanes get total)
        x += __shfl_xor(x, 1);
        x += __shfl_xor(x, 2);
        x += __shfl_xor(x, 4);
        x += __shfl_xor(x, 8);
        const float lg = x + bias;
        if (lg > m) {                          // online softmax rescale
            const float r = __expf(m - lg);
            den *= r; acc *= r; m = lg;
        }
        const float w = __expf(lg - m);
        den += w;
        acc = fmaf(w, ps, acc);
    }
    out[n * F + t] = (den > 0.0f) ? acc / den : 0.0f;
}

extern "C" void kernel_launch(void* const* d_in, const int* in_sizes, int n_in,
                              void* d_out, int out_size, void* d_ws, size_t ws_size,
                              hipStream_t stream) {
    const float* nodes     = (const float*)d_in[0];
    const int*   senders   = (const int*)  d_in[1];
    const int*   receivers = (const int*)  d_in[2];
    const float* Wsk       = (const float*)d_in[3];
    const float* Wsb       = (const float*)d_in[4];
    const float* Wrk       = (const float*)d_in[5];
    const float* Wrb       = (const float*)d_in[6];
    const float* attnk     = (const float*)d_in[7];
    const float* attnb     = (const float*)d_in[8];
    float* out = (float*)d_out;

    // workspace layout
    float* Ps     = (float*)d_ws;                            // N*F
    float* Pr     = Ps + (size_t)N_NODES * F;                // N*F
    int*   slist  = (int*)(Pr + (size_t)N_NODES * F);        // E
    int*   counts = slist + N_EDGES;                         // N
    int*   starts = counts + N_NODES;                        // N+1

    hipMemsetAsync(counts, 0, N_NODES * sizeof(int), stream);

    k_proj<<<N_NODES / RPB, 128, 0, stream>>>(nodes, Wsk, Wsb, Wrk, Wrb, Ps, Pr);

    const int e_blocks = (N_EDGES + 255) / 256;
    k_hist<<<e_blocks, 256, 0, stream>>>(receivers, counts);
    k_scan<<<1, 1024, 0, stream>>>(counts, starts);
    hipMemsetAsync(counts, 0, N_NODES * sizeof(int), stream);  // reuse as cursor
    k_fill<<<e_blocks, 256, 0, stream>>>(senders, receivers, starts, counts, slist);

    k_agg_fused<<<N_NODES, 128, 0, stream>>>(starts, slist, Ps, Pr,
                                             attnk, attnb, out);
}

// Round 6
// 335.019 us; speedup vs baseline: 18.4778x; 1.3290x over previous
//
#include <hip/hip_runtime.h>

#define N_NODES 50000
#define N_EDGES 800000
#define HEADS 8
#define HD 16
#define F 128
#define RPB 16      // rows per block in projection kernel
#define SCAN_B 1024
#define NB1 ((N_NODES + SCAN_B - 1) / SCAN_B)   // 49 scan blocks

// fast mish: x * (z^2-1)/(z^2+1), z = 1+e^x  (native exp + native rcp;
// error budget fine: threshold 6.4e-2, we sit at ~8e-3)
__device__ __forceinline__ float mish_f(float x) {
    const float ex = __expf(x);
    const float z  = 1.0f + ex;
    const float z2 = z * z;
    const float r  = __builtin_amdgcn_rcpf(z2 + 1.0f);
    const float v  = x * (z2 - 1.0f) * r;
    return (x > 20.0f) ? x : v;   // NaN in dead path for huge x is discarded
}

// sum across each 16-lane head group, pure-VALU DPP butterfly.
// steps 1,2: quad_perm xor1/xor2; steps 3,4 exploit quad-/oct-uniformity.
__device__ __forceinline__ float head16_sum(float x) {
    int v;
    v = __builtin_amdgcn_update_dpp(0, __float_as_int(x), 0xB1, 0xF, 0xF, true);
    x += __int_as_float(v);                       // + lane^1
    v = __builtin_amdgcn_update_dpp(0, __float_as_int(x), 0x4E, 0xF, 0xF, true);
    x += __int_as_float(v);                       // + lane^2
    v = __builtin_amdgcn_update_dpp(0, __float_as_int(x), 0x141, 0xF, 0xF, true);
    x += __int_as_float(v);                       // + other quad (half mirror)
    v = __builtin_amdgcn_update_dpp(0, __float_as_int(x), 0x140, 0xF, 0xF, true);
    x += __int_as_float(v);                       // + other oct (mirror)
    return x;
}

// ---- K1: dual projection GEMM: Ps = nodes@Ws + bs ; Pr = nodes@Wr + br ----
__global__ __launch_bounds__(128) void k_proj(
        const float* __restrict__ nodes,
        const float* __restrict__ Ws, const float* __restrict__ Wsb,
        const float* __restrict__ Wr, const float* __restrict__ Wrb,
        float* __restrict__ Ps, float* __restrict__ Pr) {
    __shared__ float rows[RPB][F];
    const int o  = threadIdx.x;
    const int r0 = blockIdx.x * RPB;
    for (int i = 0; i < RPB; ++i)
        rows[i][o] = nodes[(r0 + i) * F + o];
    __syncthreads();

    float accs[RPB], accr[RPB];
    const float bs = Wsb[o], br = Wrb[o];
    #pragma unroll
    for (int i = 0; i < RPB; ++i) { accs[i] = bs; accr[i] = br; }

    for (int f = 0; f < F; ++f) {
        const float ws = Ws[f * F + o];
        const float wr = Wr[f * F + o];
        #pragma unroll
        for (int i = 0; i < RPB; ++i) {
            accs[i] = fmaf(rows[i][f], ws, accs[i]);
            accr[i] = fmaf(rows[i][f], wr, accr[i]);
        }
    }
    #pragma unroll
    for (int i = 0; i < RPB; ++i) {
        Ps[(r0 + i) * F + o] = accs[i];
        Pr[(r0 + i) * F + o] = accr[i];
    }
}

// ---- CSR build: histogram -> 3-level parallel scan -> fill (sender ids) ----
__global__ __launch_bounds__(256) void k_hist(
        const int* __restrict__ receivers, int* __restrict__ counts) {
    const int e = blockIdx.x * blockDim.x + threadIdx.x;
    if (e < N_EDGES) atomicAdd(counts + receivers[e], 1);
}

__global__ __launch_bounds__(1024) void k_scan1(
        const int* __restrict__ counts, int* __restrict__ starts,
        int* __restrict__ partials) {
    __shared__ int buf[SCAN_B];
    const int i = blockIdx.x * SCAN_B + threadIdx.x;
    const int v = (i < N_NODES) ? counts[i] : 0;
    buf[threadIdx.x] = v;
    __syncthreads();
    for (int off = 1; off < SCAN_B; off <<= 1) {
        const int t = (threadIdx.x >= (unsigned)off) ? buf[threadIdx.x - off] : 0;
        __syncthreads();
        buf[threadIdx.x] += t;
        __syncthreads();
    }
    if (i < N_NODES) starts[i] = buf[threadIdx.x] - v;   // block-local exclusive
    if (threadIdx.x == SCAN_B - 1) partials[blockIdx.x] = buf[SCAN_B - 1];
}

__global__ __launch_bounds__(64) void k_scan2(
        int* __restrict__ partials, int* __restrict__ starts) {
    __shared__ int buf[64];
    const int t = threadIdx.x;
    const int v = (t < NB1) ? partials[t] : 0;
    buf[t] = v;
    __syncthreads();
    for (int off = 1; off < 64; off <<= 1) {
        const int u = (t >= (unsigned)off) ? buf[t - off] : 0;
        __syncthreads();
        buf[t] += u;
        __syncthreads();
    }
    if (t < NB1) partials[t] = buf[t] - v;               // exclusive offsets
    if (t == 0) starts[N_NODES] = N_EDGES;
}

__global__ __launch_bounds__(1024) void k_scan3(
        const int* __restrict__ partials, int* __restrict__ starts) {
    const int i = blockIdx.x * SCAN_B + threadIdx.x;
    if (i < N_NODES) starts[i] += partials[blockIdx.x];
}

__global__ __launch_bounds__(256) void k_fill(
        const int* __restrict__ senders, const int* __restrict__ receivers,
        const int* __restrict__ starts, int* __restrict__ cursor,
        int* __restrict__ slist) {
    const int e = blockIdx.x * blockDim.x + threadIdx.x;
    if (e >= N_EDGES) return;
    const int r = receivers[e];
    const int pos = atomicAdd(cursor + r, 1);
    slist[starts[r] + pos] = senders[e];
}

// ---- K4: fused logits + online softmax + aggregation (branchless) ----
__global__ __launch_bounds__(128) void k_agg_fused(
        const int* __restrict__ starts, const int* __restrict__ slist,
        const float* __restrict__ Ps, const float* __restrict__ Pr,
        const float* __restrict__ attn_k, const float* __restrict__ attn_b,
        float* __restrict__ out) {
    const int n = blockIdx.x;
    const int t = threadIdx.x;
    const int e0 = starts[n], e1 = starts[n + 1];
    const float pr = Pr[n * F + t];
    const float ak = attn_k[t & 15];
    const float bias = attn_b[0];

    float m = -3.0e38f, den = 0.0f, acc = 0.0f;
    int   s_nxt = 0;
    float ps_nxt = 0.0f;
    if (e0 < e1) { s_nxt = slist[e0]; ps_nxt = Ps[s_nxt * F + t]; }

    for (int i = e0; i < e1; ++i) {
        const float ps = ps_nxt;
        if (i + 1 < e1) {                       // prefetch next sender row
            s_nxt  = slist[i + 1];
            ps_nxt = Ps[s_nxt * F + t];
        }
        const float lg = head16_sum(mish_f(ps + pr) * ak) + bias;
        const float mn = fmaxf(m, lg);          // branchless online softmax
        const float cr = __expf(m - mn);        // ==1 unless new max
        const float w  = __expf(lg - mn);
        den = fmaf(den, cr, w);
        acc = fmaf(w, ps, acc * cr);
        m = mn;
    }
    out[n * F + t] = (den > 0.0f) ? acc / den : 0.0f;
}

extern "C" void kernel_launch(void* const* d_in, const int* in_sizes, int n_in,
                              void* d_out, int out_size, void* d_ws, size_t ws_size,
                              hipStream_t stream) {
    const float* nodes     = (const float*)d_in[0];
    const int*   senders   = (const int*)  d_in[1];
    const int*   receivers = (const int*)  d_in[2];
    const float* Wsk       = (const float*)d_in[3];
    const float* Wsb       = (const float*)d_in[4];
    const float* Wrk       = (const float*)d_in[5];
    const float* Wrb       = (const float*)d_in[6];
    const float* attnk     = (const float*)d_in[7];
    const float* attnb     = (const float*)d_in[8];
    float* out = (float*)d_out;

    // workspace layout
    float* Ps       = (float*)d_ws;                          // N*F
    float* Pr       = Ps + (size_t)N_NODES * F;              // N*F
    int*   slist    = (int*)(Pr + (size_t)N_NODES * F);      // E
    int*   counts   = slist + N_EDGES;                       // N
    int*   starts   = counts + N_NODES;                      // N+1
    int*   partials = starts + N_NODES + 1;                  // NB1 (<64)

    hipMemsetAsync(counts, 0, N_NODES * sizeof(int), stream);

    k_proj<<<N_NODES / RPB, 128, 0, stream>>>(nodes, Wsk, Wsb, Wrk, Wrb, Ps, Pr);

    const int e_blocks = (N_EDGES + 255) / 256;
    k_hist<<<e_blocks, 256, 0, stream>>>(receivers, counts);
    k_scan1<<<NB1, SCAN_B, 0, stream>>>(counts, starts, partials);
    k_scan2<<<1, 64, 0, stream>>>(partials, starts);
    k_scan3<<<NB1, SCAN_B, 0, stream>>>(partials, starts);
    hipMemsetAsync(counts, 0, N_NODES * sizeof(int), stream);  // reuse as cursor
    k_fill<<<e_blocks, 256, 0, stream>>>(senders, receivers, starts, counts, slist);

    k_agg_fused<<<N_NODES, 128, 0, stream>>>(starts, slist, Ps, Pr,
                                             attnk, attnb, out);
}

// Round 7
// 320.562 us; speedup vs baseline: 19.3112x; 1.0451x over previous
//
#include <hip/hip_runtime.h>

#define N_NODES 50000
#define N_EDGES 800000
#define HEADS 8
#define HD 16
#define F 128
#define RPB 16      // rows per block in projection kernel
#define SCAN_B 1024
#define NB1 ((N_NODES + SCAN_B - 1) / SCAN_B)   // 49 scan blocks
#define TILE 8      // edges per k_agg_fused inner tile

// sum across each 16-lane head group, pure-VALU DPP butterfly.
__device__ __forceinline__ float head16_sum(float x) {
    int v;
    v = __builtin_amdgcn_update_dpp(0, __float_as_int(x), 0xB1, 0xF, 0xF, true);
    x += __int_as_float(v);                       // + lane^1
    v = __builtin_amdgcn_update_dpp(0, __float_as_int(x), 0x4E, 0xF, 0xF, true);
    x += __int_as_float(v);                       // + lane^2
    v = __builtin_amdgcn_update_dpp(0, __float_as_int(x), 0x141, 0xF, 0xF, true);
    x += __int_as_float(v);                       // + other quad (half mirror)
    v = __builtin_amdgcn_update_dpp(0, __float_as_int(x), 0x140, 0xF, 0xF, true);
    x += __int_as_float(v);                       // + other oct (mirror)
    return x;
}

// ---- K1: dual projection GEMM: Ps = nodes@Ws + bs ; Pr = nodes@Wr + br ----
__global__ __launch_bounds__(128) void k_proj(
        const float* __restrict__ nodes,
        const float* __restrict__ Ws, const float* __restrict__ Wsb,
        const float* __restrict__ Wr, const float* __restrict__ Wrb,
        float* __restrict__ Ps, float* __restrict__ Pr) {
    __shared__ float rows[RPB][F];
    const int o  = threadIdx.x;
    const int r0 = blockIdx.x * RPB;
    for (int i = 0; i < RPB; ++i)
        rows[i][o] = nodes[(r0 + i) * F + o];
    __syncthreads();

    float accs[RPB], accr[RPB];
    const float bs = Wsb[o], br = Wrb[o];
    #pragma unroll
    for (int i = 0; i < RPB; ++i) { accs[i] = bs; accr[i] = br; }

    for (int f = 0; f < F; ++f) {
        const float ws = Ws[f * F + o];
        const float wr = Wr[f * F + o];
        #pragma unroll
        for (int i = 0; i < RPB; ++i) {
            accs[i] = fmaf(rows[i][f], ws, accs[i]);
            accr[i] = fmaf(rows[i][f], wr, accr[i]);
        }
    }
    #pragma unroll
    for (int i = 0; i < RPB; ++i) {
        Ps[(r0 + i) * F + o] = accs[i];
        Pr[(r0 + i) * F + o] = accr[i];
    }
}

// ---- CSR build: histogram -> 2-level scan -> fill (sender ids) ----
__global__ __launch_bounds__(256) void k_hist(
        const int* __restrict__ receivers, int* __restrict__ counts) {
    const int e = blockIdx.x * blockDim.x + threadIdx.x;
    if (e < N_EDGES) atomicAdd(counts + receivers[e], 1);
}

__global__ __launch_bounds__(1024) void k_scan1(
        const int* __restrict__ counts, int* __restrict__ starts,
        int* __restrict__ partials) {
    __shared__ int buf[SCAN_B];
    const int i = blockIdx.x * SCAN_B + threadIdx.x;
    const int v = (i < N_NODES) ? counts[i] : 0;
    buf[threadIdx.x] = v;
    __syncthreads();
    for (int off = 1; off < SCAN_B; off <<= 1) {
        const int t = (threadIdx.x >= (unsigned)off) ? buf[threadIdx.x - off] : 0;
        __syncthreads();
        buf[threadIdx.x] += t;
        __syncthreads();
    }
    if (i < N_NODES) starts[i] = buf[threadIdx.x] - v;   // block-local exclusive
    if (threadIdx.x == SCAN_B - 1) partials[blockIdx.x] = buf[SCAN_B - 1];
}

// merged scan2+scan3: block b adds exclusive-sum(partials[0..b)) to its slice
__global__ __launch_bounds__(1024) void k_scan23(
        const int* __restrict__ partials, int* __restrict__ starts) {
    __shared__ int s_off;
    if (threadIdx.x < 64) {
        const int j = (int)threadIdx.x;
        int v = (j < (int)blockIdx.x && j < NB1) ? partials[j] : 0;
        v += __shfl_xor(v, 1);  v += __shfl_xor(v, 2);  v += __shfl_xor(v, 4);
        v += __shfl_xor(v, 8);  v += __shfl_xor(v, 16); v += __shfl_xor(v, 32);
        if (threadIdx.x == 0) s_off = v;
    }
    if (threadIdx.x == 0 && blockIdx.x == 0) starts[N_NODES] = N_EDGES;
    __syncthreads();
    const int i = blockIdx.x * SCAN_B + threadIdx.x;
    if (i < N_NODES) starts[i] += s_off;
}

__global__ __launch_bounds__(256) void k_fill(
        const int* __restrict__ senders, const int* __restrict__ receivers,
        const int* __restrict__ starts, int* __restrict__ cursor,
        int* __restrict__ slist) {
    const int e = blockIdx.x * blockDim.x + threadIdx.x;
    if (e >= N_EDGES) return;
    const int r = receivers[e];
    const int pos = atomicAdd(cursor + r, 1);
    slist[starts[r] + pos] = senders[e];
}

// ---- K4: fused logits + tiled deferred-max softmax + aggregation ----
__global__ __launch_bounds__(128) void k_agg_fused(
        const int* __restrict__ starts, const int* __restrict__ slist,
        const float* __restrict__ Ps, const float* __restrict__ Pr,
        const float* __restrict__ attn_k, const float* __restrict__ attn_b,
        float* __restrict__ out) {
    const int n = blockIdx.x;
    const int t = threadIdx.x;
    const int e0 = starts[n], e1 = starts[n + 1];
    const float pr = Pr[n * F + t];
    const float ak = attn_k[t & 15];
    const float bias = attn_b[0];

    float m = -3.0e38f, den = 0.0f, acc = 0.0f;

    for (int i = e0; i < e1; i += TILE) {
        float psv[TILE], lg[TILE];
        // 8 gathers in flight (uniform slist index -> SALU/scalar load)
        #pragma unroll
        for (int k = 0; k < TILE; ++k) {
            const int idx = (i + k < e1) ? (i + k) : (e1 - 1);
            psv[k] = Ps[slist[idx] * F + t];
        }
        // logits: mish(ps+pr)*ak summed over the 16-lane head group
        #pragma unroll
        for (int k = 0; k < TILE; ++k) {
            const float x  = psv[k] + pr;
            const float ex = __expf(x);
            const float z  = 1.0f + ex;
            const float zz = fmaf(z, z, 1.0f);          // z^2 + 1
            const float r  = __builtin_amdgcn_rcpf(zz); // overflow -> 0 -> v=x
            const float v  = fmaf(-2.0f * x, r, x) * ak;
            const float sum = head16_sum(v);
            lg[k] = (i + k < e1) ? (sum + bias) : -3.0e38f;  // SALU mask
        }
        // tile max, single rescale
        float tm = lg[0];
        #pragma unroll
        for (int k = 1; k < TILE; ++k) tm = fmaxf(tm, lg[k]);
        const float mn = fmaxf(m, tm);
        const float cr = __expf(m - mn);   // first tile: exp(-huge)=0, den/acc already 0
        den *= cr;  acc *= cr;  m = mn;
        // accumulate (masked lanes get w = exp(-huge) = 0)
        #pragma unroll
        for (int k = 0; k < TILE; ++k) {
            const float w = __expf(lg[k] - mn);
            den += w;
            acc = fmaf(w, psv[k], acc);
        }
    }
    out[n * F + t] = (den > 0.0f) ? acc / den : 0.0f;
}

extern "C" void kernel_launch(void* const* d_in, const int* in_sizes, int n_in,
                              void* d_out, int out_size, void* d_ws, size_t ws_size,
                              hipStream_t stream) {
    const float* nodes     = (const float*)d_in[0];
    const int*   senders   = (const int*)  d_in[1];
    const int*   receivers = (const int*)  d_in[2];
    const float* Wsk       = (const float*)d_in[3];
    const float* Wsb       = (const float*)d_in[4];
    const float* Wrk       = (const float*)d_in[5];
    const float* Wrb       = (const float*)d_in[6];
    const float* attnk     = (const float*)d_in[7];
    const float* attnb     = (const float*)d_in[8];
    float* out = (float*)d_out;

    // workspace layout
    float* Ps       = (float*)d_ws;                          // N*F
    float* Pr       = Ps + (size_t)N_NODES * F;              // N*F
    int*   slist    = (int*)(Pr + (size_t)N_NODES * F);      // E
    int*   counts   = slist + N_EDGES;                       // N
    int*   cursor   = counts + N_NODES;                      // N
    int*   starts   = cursor + N_NODES;                      // N+1
    int*   partials = starts + N_NODES + 1;                  // NB1 (<64)

    // one memset zeroes both counts and cursor (adjacent)
    hipMemsetAsync(counts, 0, 2 * N_NODES * sizeof(int), stream);

    k_proj<<<N_NODES / RPB, 128, 0, stream>>>(nodes, Wsk, Wsb, Wrk, Wrb, Ps, Pr);

    const int e_blocks = (N_EDGES + 255) / 256;
    k_hist<<<e_blocks, 256, 0, stream>>>(receivers, counts);
    k_scan1<<<NB1, SCAN_B, 0, stream>>>(counts, starts, partials);
    k_scan23<<<NB1, SCAN_B, 0, stream>>>(partials, starts);
    k_fill<<<e_blocks, 256, 0, stream>>>(senders, receivers, starts, cursor, slist);

    k_agg_fused<<<N_NODES, 128, 0, stream>>>(starts, slist, Ps, Pr,
                                             attnk, attnb, out);
}

// Round 8
// 312.228 us; speedup vs baseline: 19.8266x; 1.0267x over previous
//
#include <hip/hip_runtime.h>

#define N_NODES 50000
#define N_EDGES 800000
#define HEADS 8
#define HD 16
#define F 128
#define RPB 16      // rows per block in projection kernel
#define SCAN_B 1024
#define NB1 ((N_NODES + SCAN_B - 1) / SCAN_B)   // 49 scan blocks
#define TILE 8      // edges per k_agg_fused inner tile

// sum across each 16-lane head group, pure-VALU DPP butterfly.
__device__ __forceinline__ float head16_sum(float x) {
    int v;
    v = __builtin_amdgcn_update_dpp(0, __float_as_int(x), 0xB1, 0xF, 0xF, true);
    x += __int_as_float(v);                       // + lane^1
    v = __builtin_amdgcn_update_dpp(0, __float_as_int(x), 0x4E, 0xF, 0xF, true);
    x += __int_as_float(v);                       // + lane^2
    v = __builtin_amdgcn_update_dpp(0, __float_as_int(x), 0x141, 0xF, 0xF, true);
    x += __int_as_float(v);                       // + other quad (half mirror)
    v = __builtin_amdgcn_update_dpp(0, __float_as_int(x), 0x140, 0xF, 0xF, true);
    x += __int_as_float(v);                       // + other oct (mirror)
    return x;
}

// ---- K1: dual projection GEMM + fused receiver histogram.
//      3125 blocks x 128 threads; block b also counts edges [b*256,(b+1)*256).
__global__ __launch_bounds__(128) void k_proj_hist(
        const float* __restrict__ nodes,
        const float* __restrict__ Ws, const float* __restrict__ Wsb,
        const float* __restrict__ Wr, const float* __restrict__ Wrb,
        const int* __restrict__ receivers, int* __restrict__ counts,
        float* __restrict__ Ps, float* __restrict__ Pr) {
    __shared__ float rows[RPB][F];
    const int o  = threadIdx.x;
    const int r0 = blockIdx.x * RPB;

    // fire-and-forget histogram atomics; latency hides under the GEMM
    const int ebase = blockIdx.x * 256 + o;
    atomicAdd(counts + receivers[ebase], 1);
    atomicAdd(counts + receivers[ebase + 128], 1);

    for (int i = 0; i < RPB; ++i)
        rows[i][o] = nodes[(r0 + i) * F + o];
    __syncthreads();

    float accs[RPB], accr[RPB];
    const float bs = Wsb[o], br = Wrb[o];
    #pragma unroll
    for (int i = 0; i < RPB; ++i) { accs[i] = bs; accr[i] = br; }

    for (int f = 0; f < F; ++f) {
        const float ws = Ws[f * F + o];
        const float wr = Wr[f * F + o];
        #pragma unroll
        for (int i = 0; i < RPB; ++i) {
            accs[i] = fmaf(rows[i][f], ws, accs[i]);
            accr[i] = fmaf(rows[i][f], wr, accr[i]);
        }
    }
    #pragma unroll
    for (int i = 0; i < RPB; ++i) {
        Ps[(r0 + i) * F + o] = accs[i];
        Pr[(r0 + i) * F + o] = accr[i];
    }
}

// ---- scan1: block-local exclusive scan of counts + per-block totals ----
__global__ __launch_bounds__(1024) void k_scan1(
        const int* __restrict__ counts, int* __restrict__ starts,
        int* __restrict__ partials) {
    __shared__ int buf[SCAN_B];
    const int i = blockIdx.x * SCAN_B + threadIdx.x;
    const int v = (i < N_NODES) ? counts[i] : 0;
    buf[threadIdx.x] = v;
    __syncthreads();
    for (int off = 1; off < SCAN_B; off <<= 1) {
        const int t = (threadIdx.x >= (unsigned)off) ? buf[threadIdx.x - off] : 0;
        __syncthreads();
        buf[threadIdx.x] += t;
        __syncthreads();
    }
    if (i < N_NODES) starts[i] = buf[threadIdx.x] - v;   // block-local exclusive
    if (threadIdx.x == SCAN_B - 1) partials[blockIdx.x] = buf[SCAN_B - 1];
}

// ---- fill: global start = starts[r] + prefix(partials)[r>>10], computed
//      per block via one 64-lane shfl scan into LDS ----
__global__ __launch_bounds__(256) void k_fill(
        const int* __restrict__ senders, const int* __restrict__ receivers,
        const int* __restrict__ starts, const int* __restrict__ partials,
        int* __restrict__ cursor, int* __restrict__ slist) {
    __shared__ int off_lds[NB1];
    if (threadIdx.x < 64) {
        const int j = (int)threadIdx.x;
        const int v = (j < NB1) ? partials[j] : 0;
        int incl = v;
        #pragma unroll
        for (int d = 1; d < 64; d <<= 1) {
            const int u = __shfl_up(incl, d);
            if (j >= d) incl += u;
        }
        if (j < NB1) off_lds[j] = incl - v;              // exclusive
    }
    __syncthreads();
    const int e = blockIdx.x * 256 + (int)threadIdx.x;   // 3125*256 == N_EDGES
    const int r = receivers[e];
    const int pos = atomicAdd(cursor + r, 1);
    slist[starts[r] + off_lds[r >> 10] + pos] = senders[e];
}

// ---- K4: fused logits + no-max softmax + aggregation.
//      softmax is shift-invariant: no max tracking, no bias (cancels). ----
__global__ __launch_bounds__(128) void k_agg_fused(
        const int* __restrict__ starts, const int* __restrict__ counts,
        const int* __restrict__ partials, const int* __restrict__ slist,
        const float* __restrict__ Ps, const float* __restrict__ Pr,
        const float* __restrict__ attn_k,
        float* __restrict__ out) {
    const int n = blockIdx.x;
    const int t = threadIdx.x;

    // per-wave: off = sum(partials[j] for j < n>>10)   (both waves identical)
    const int sb = n >> 10;
    const int lane = t & 63;
    int v = (lane < sb) ? partials[lane] : 0;
    v += __shfl_xor(v, 1);  v += __shfl_xor(v, 2);  v += __shfl_xor(v, 4);
    v += __shfl_xor(v, 8);  v += __shfl_xor(v, 16); v += __shfl_xor(v, 32);

    const int e0 = starts[n] + v;
    const int e1 = e0 + counts[n];
    const float pr = Pr[n * F + t];
    const float ak = attn_k[t & 15];

    float den = 0.0f, acc = 0.0f;

    for (int i = e0; i < e1; i += TILE) {
        float psv[TILE];
        #pragma unroll
        for (int k = 0; k < TILE; ++k) {
            const int idx = (i + k < e1) ? (i + k) : (e1 - 1);
            psv[k] = Ps[slist[idx] * F + t];
        }
        #pragma unroll
        for (int k = 0; k < TILE; ++k) {
            const float x  = psv[k] + pr;
            const float ex = __expf(x);
            const float z  = 1.0f + ex;
            const float zz = fmaf(z, z, 1.0f);           // z^2 + 1
            const float r  = __builtin_amdgcn_rcpf(zz);  // overflow -> 0 -> v = x
            const float mi = fmaf(-2.0f * x, r, x) * ak; // mish(x)*ak
            const float sum = head16_sum(mi);
            const float w = (i + k < e1) ? __expf(sum) : 0.0f;
            den += w;
            acc = fmaf(w, psv[k], acc);
        }
    }
    out[n * F + t] = (den > 0.0f) ? acc / den : 0.0f;
}

extern "C" void kernel_launch(void* const* d_in, const int* in_sizes, int n_in,
                              void* d_out, int out_size, void* d_ws, size_t ws_size,
                              hipStream_t stream) {
    const float* nodes     = (const float*)d_in[0];
    const int*   senders   = (const int*)  d_in[1];
    const int*   receivers = (const int*)  d_in[2];
    const float* Wsk       = (const float*)d_in[3];
    const float* Wsb       = (const float*)d_in[4];
    const float* Wrk       = (const float*)d_in[5];
    const float* Wrb       = (const float*)d_in[6];
    const float* attnk     = (const float*)d_in[7];
    float* out = (float*)d_out;

    // workspace layout
    float* Ps       = (float*)d_ws;                          // N*F
    float* Pr       = Ps + (size_t)N_NODES * F;              // N*F
    int*   slist    = (int*)(Pr + (size_t)N_NODES * F);      // E
    int*   counts   = slist + N_EDGES;                       // N
    int*   cursor   = counts + N_NODES;                      // N
    int*   starts   = cursor + N_NODES;                      // N (block-local)
    int*   partials = starts + N_NODES + 1;                  // NB1 (<64)

    // one memset zeroes both counts and cursor (adjacent)
    hipMemsetAsync(counts, 0, 2 * N_NODES * sizeof(int), stream);

    k_proj_hist<<<N_NODES / RPB, 128, 0, stream>>>(nodes, Wsk, Wsb, Wrk, Wrb,
                                                   receivers, counts, Ps, Pr);
    k_scan1<<<NB1, SCAN_B, 0, stream>>>(counts, starts, partials);
    k_fill<<<N_EDGES / 256, 256, 0, stream>>>(senders, receivers, starts,
                                              partials, cursor, slist);
    k_agg_fused<<<N_NODES, 128, 0, stream>>>(starts, counts, partials, slist,
                                             Ps, Pr, attnk, out);
}

// Round 9
// 282.730 us; speedup vs baseline: 21.8952x; 1.1043x over previous
//
#include <hip/hip_runtime.h>

#define N_NODES 50000
#define N_EDGES 800000
#define HEADS 8
#define HD 16
#define F 128
#define RPB 16      // rows per block in projection kernel
#define SCAN_B 1024
#define NB1 ((N_NODES + SCAN_B - 1) / SCAN_B)   // 49 scan blocks
#define TILE 8      // edges per k_agg_fused inner tile

// mish(x) = x - 2x/(z^2+1), z = 1+e^x  (native exp + rcp; rcp(inf)=0 -> x)
__device__ __forceinline__ float mish_x(float x) {
    const float ex = __expf(x);
    const float z  = 1.0f + ex;
    const float zz = fmaf(z, z, 1.0f);
    const float r  = __builtin_amdgcn_rcpf(zz);
    return fmaf(-2.0f * x, r, x);
}

// sum across each 8-lane head group (lanes 8h..8h+7), pure-VALU DPP.
__device__ __forceinline__ float head8_sum(float x) {
    int v;
    v = __builtin_amdgcn_update_dpp(0, __float_as_int(x), 0xB1, 0xF, 0xF, true);
    x += __int_as_float(v);                       // + lane^1 (quad perm)
    v = __builtin_amdgcn_update_dpp(0, __float_as_int(x), 0x4E, 0xF, 0xF, true);
    x += __int_as_float(v);                       // + lane^2 (quad perm)
    v = __builtin_amdgcn_update_dpp(0, __float_as_int(x), 0x141, 0xF, 0xF, true);
    x += __int_as_float(v);                       // + other quad (half mirror)
    return x;
}

// ---- K1: dual projection GEMM + fused receiver histogram ----
__global__ __launch_bounds__(128) void k_proj_hist(
        const float* __restrict__ nodes,
        const float* __restrict__ Ws, const float* __restrict__ Wsb,
        const float* __restrict__ Wr, const float* __restrict__ Wrb,
        const int* __restrict__ receivers, int* __restrict__ counts,
        float* __restrict__ Ps, float* __restrict__ Pr) {
    __shared__ float rows[RPB][F];
    const int o  = threadIdx.x;
    const int r0 = blockIdx.x * RPB;

    // fire-and-forget histogram atomics; latency hides under the GEMM
    const int ebase = blockIdx.x * 256 + o;
    atomicAdd(counts + receivers[ebase], 1);
    atomicAdd(counts + receivers[ebase + 128], 1);

    for (int i = 0; i < RPB; ++i)
        rows[i][o] = nodes[(r0 + i) * F + o];
    __syncthreads();

    float accs[RPB], accr[RPB];
    const float bs = Wsb[o], br = Wrb[o];
    #pragma unroll
    for (int i = 0; i < RPB; ++i) { accs[i] = bs; accr[i] = br; }

    for (int f = 0; f < F; ++f) {
        const float ws = Ws[f * F + o];
        const float wr = Wr[f * F + o];
        #pragma unroll
        for (int i = 0; i < RPB; ++i) {
            accs[i] = fmaf(rows[i][f], ws, accs[i]);
            accr[i] = fmaf(rows[i][f], wr, accr[i]);
        }
    }
    #pragma unroll
    for (int i = 0; i < RPB; ++i) {
        Ps[(r0 + i) * F + o] = accs[i];
        Pr[(r0 + i) * F + o] = accr[i];
    }
}

// ---- scan1: block-local exclusive scan of counts + per-block totals ----
__global__ __launch_bounds__(1024) void k_scan1(
        const int* __restrict__ counts, int* __restrict__ starts,
        int* __restrict__ partials) {
    __shared__ int buf[SCAN_B];
    const int i = blockIdx.x * SCAN_B + threadIdx.x;
    const int v = (i < N_NODES) ? counts[i] : 0;
    buf[threadIdx.x] = v;
    __syncthreads();
    for (int off = 1; off < SCAN_B; off <<= 1) {
        const int t = (threadIdx.x >= (unsigned)off) ? buf[threadIdx.x - off] : 0;
        __syncthreads();
        buf[threadIdx.x] += t;
        __syncthreads();
    }
    if (i < N_NODES) starts[i] = buf[threadIdx.x] - v;   // block-local exclusive
    if (threadIdx.x == SCAN_B - 1) partials[blockIdx.x] = buf[SCAN_B - 1];
}

// ---- fill: global start = starts[r] + prefix(partials)[r>>10] ----
__global__ __launch_bounds__(256) void k_fill(
        const int* __restrict__ senders, const int* __restrict__ receivers,
        const int* __restrict__ starts, const int* __restrict__ partials,
        int* __restrict__ cursor, int* __restrict__ slist) {
    __shared__ int off_lds[NB1];
    if (threadIdx.x < 64) {
        const int j = (int)threadIdx.x;
        const int v = (j < NB1) ? partials[j] : 0;
        int incl = v;
        #pragma unroll
        for (int d = 1; d < 64; d <<= 1) {
            const int u = __shfl_up(incl, d);
            if (j >= d) incl += u;
        }
        if (j < NB1) off_lds[j] = incl - v;              // exclusive
    }
    __syncthreads();
    const int e = blockIdx.x * 256 + (int)threadIdx.x;   // 3125*256 == N_EDGES
    const int r = receivers[e];
    const int pos = atomicAdd(cursor + r, 1);
    slist[starts[r] + off_lds[r >> 10] + pos] = senders[e];
}

// ---- K4: fused logits + no-max softmax + aggregation.
//      ONE WAVE per node, 2 dims per lane (float2); 4 nodes per 256-block.
//      Wave-uniform node id via readfirstlane -> scalar loads for
//      starts/counts/slist; double-buffered 8-edge tile prefetch. ----
__global__ __launch_bounds__(256) void k_agg_fused(
        const int* __restrict__ starts, const int* __restrict__ counts,
        const int* __restrict__ partials, const int* __restrict__ slist,
        const float* __restrict__ Ps, const float* __restrict__ Pr,
        const float* __restrict__ attn_k, float* __restrict__ out) {
    const int lane = (int)threadIdx.x & 63;
    const int n = __builtin_amdgcn_readfirstlane(
                      blockIdx.x * 4 + ((int)threadIdx.x >> 6));
    const int d0 = lane << 1;                 // dims d0, d0+1; head = lane>>3

    // offset of this node's superblock: sum(partials[j] for j < n>>10)
    const int sb = n >> 10;
    int v = (lane < sb) ? partials[lane] : 0;
    v += __shfl_xor(v, 1);  v += __shfl_xor(v, 2);  v += __shfl_xor(v, 4);
    v += __shfl_xor(v, 8);  v += __shfl_xor(v, 16); v += __shfl_xor(v, 32);

    const int e0 = starts[n] + v;
    const int e1 = e0 + counts[n];
    const float2 pr2 = *(const float2*)(Pr + (size_t)n * F + d0);
    const float2 ak2 = *(const float2*)(attn_k + (d0 & 15));

    float den = 0.0f, ax = 0.0f, ay = 0.0f;

    if (e1 > e0) {
        float2 cur[TILE], nxt[TILE];
        #pragma unroll
        for (int k = 0; k < TILE; ++k) {
            const int idx = (e0 + k < e1) ? e0 + k : e1 - 1;
            cur[k] = *(const float2*)(Ps + (size_t)slist[idx] * F + d0);
        }
        for (int i = e0; i < e1; i += TILE) {
            const bool more = (i + TILE) < e1;    // wave-uniform
            if (more) {
                #pragma unroll
                for (int k = 0; k < TILE; ++k) {
                    const int idx = (i + TILE + k < e1) ? i + TILE + k : e1 - 1;
                    nxt[k] = *(const float2*)(Ps + (size_t)slist[idx] * F + d0);
                }
            }
            #pragma unroll
            for (int k = 0; k < TILE; ++k) {
                const float mi = mish_x(cur[k].x + pr2.x) * ak2.x
                               + mish_x(cur[k].y + pr2.y) * ak2.y;
                const float s = head8_sum(mi);
                const float w = (i + k < e1) ? __expf(s) : 0.0f;
                den += w;
                ax = fmaf(w, cur[k].x, ax);
                ay = fmaf(w, cur[k].y, ay);
            }
            if (more) {
                #pragma unroll
                for (int k = 0; k < TILE; ++k) cur[k] = nxt[k];
            }
        }
    }
    const float inv = __builtin_amdgcn_rcpf(den);
    float2 o2;
    o2.x = (den > 0.0f) ? ax * inv : 0.0f;
    o2.y = (den > 0.0f) ? ay * inv : 0.0f;
    *(float2*)(out + (size_t)n * F + d0) = o2;
}

extern "C" void kernel_launch(void* const* d_in, const int* in_sizes, int n_in,
                              void* d_out, int out_size, void* d_ws, size_t ws_size,
                              hipStream_t stream) {
    const float* nodes     = (const float*)d_in[0];
    const int*   senders   = (const int*)  d_in[1];
    const int*   receivers = (const int*)  d_in[2];
    const float* Wsk       = (const float*)d_in[3];
    const float* Wsb       = (const float*)d_in[4];
    const float* Wrk       = (const float*)d_in[5];
    const float* Wrb       = (const float*)d_in[6];
    const float* attnk     = (const float*)d_in[7];
    float* out = (float*)d_out;

    // workspace layout
    float* Ps       = (float*)d_ws;                          // N*F
    float* Pr       = Ps + (size_t)N_NODES * F;              // N*F
    int*   slist    = (int*)(Pr + (size_t)N_NODES * F);      // E
    int*   counts   = slist + N_EDGES;                       // N
    int*   cursor   = counts + N_NODES;                      // N
    int*   starts   = cursor + N_NODES;                      // N (block-local)
    int*   partials = starts + N_NODES + 1;                  // NB1 (<64)

    // one memset zeroes both counts and cursor (adjacent)
    hipMemsetAsync(counts, 0, 2 * N_NODES * sizeof(int), stream);

    k_proj_hist<<<N_NODES / RPB, 128, 0, stream>>>(nodes, Wsk, Wsb, Wrk, Wrb,
                                                   receivers, counts, Ps, Pr);
    k_scan1<<<NB1, SCAN_B, 0, stream>>>(counts, starts, partials);
    k_fill<<<N_EDGES / 256, 256, 0, stream>>>(senders, receivers, starts,
                                              partials, cursor, slist);
    k_agg_fused<<<N_NODES / 4, 256, 0, stream>>>(starts, counts, partials,
                                                 slist, Ps, Pr, attnk, out);
}